// Round 4
// baseline (5538.050 us; speedup 1.0000x reference)
//
#include <hip/hip_runtime.h>
#include <hip/hip_bf16.h>

typedef __hip_bfloat16 bf16;
typedef short bf16x8 __attribute__((ext_vector_type(8)));
typedef float f32x4 __attribute__((ext_vector_type(4)));
typedef unsigned long long u64;
typedef unsigned int u32;

#define MFMA16(A, B, C) __builtin_amdgcn_mfma_f32_16x16x32_bf16(A, B, C, 0, 0, 0)

__device__ __forceinline__ float sigf(float x) { return 1.f / (1.f + __expf(-x)); }
__device__ __forceinline__ float tanh_fast(float x) { return 2.f / (1.f + __expf(-2.f * x)) - 1.f; }

__device__ __forceinline__ bf16x8 pack8(f32x4 f0, f32x4 f1) {
  union { short s[8]; bf16x8 v8; } o;
  o.s[0] = __builtin_bit_cast(short, __float2bfloat16(f0[0]));
  o.s[1] = __builtin_bit_cast(short, __float2bfloat16(f0[1]));
  o.s[2] = __builtin_bit_cast(short, __float2bfloat16(f0[2]));
  o.s[3] = __builtin_bit_cast(short, __float2bfloat16(f0[3]));
  o.s[4] = __builtin_bit_cast(short, __float2bfloat16(f1[0]));
  o.s[5] = __builtin_bit_cast(short, __float2bfloat16(f1[1]));
  o.s[6] = __builtin_bit_cast(short, __float2bfloat16(f1[2]));
  o.s[7] = __builtin_bit_cast(short, __float2bfloat16(f1[3]));
  return o.v8;
}

// ---- 16-chunk A-row gather through the local XCD L2 (sc0 = bypass L1, hit
// L2). h is row-major [64][512] bf16 per t, so one per-lane base + imm
// offsets covers a full K=512 A-fragment row. waitcnt inside the block; all
// consumers are data-dependent on the outputs, so ordering is by dataflow.
__device__ __forceinline__ void gl2_16(u64 base, f32x4 a[16]) {
  asm volatile(
      "global_load_dwordx4 %0, %16, off sc0\n\t"
      "global_load_dwordx4 %1, %16, off offset:64 sc0\n\t"
      "global_load_dwordx4 %2, %16, off offset:128 sc0\n\t"
      "global_load_dwordx4 %3, %16, off offset:192 sc0\n\t"
      "global_load_dwordx4 %4, %16, off offset:256 sc0\n\t"
      "global_load_dwordx4 %5, %16, off offset:320 sc0\n\t"
      "global_load_dwordx4 %6, %16, off offset:384 sc0\n\t"
      "global_load_dwordx4 %7, %16, off offset:448 sc0\n\t"
      "global_load_dwordx4 %8, %16, off offset:512 sc0\n\t"
      "global_load_dwordx4 %9, %16, off offset:576 sc0\n\t"
      "global_load_dwordx4 %10, %16, off offset:640 sc0\n\t"
      "global_load_dwordx4 %11, %16, off offset:704 sc0\n\t"
      "global_load_dwordx4 %12, %16, off offset:768 sc0\n\t"
      "global_load_dwordx4 %13, %16, off offset:832 sc0\n\t"
      "global_load_dwordx4 %14, %16, off offset:896 sc0\n\t"
      "global_load_dwordx4 %15, %16, off offset:960 sc0\n\t"
      "s_waitcnt vmcnt(0)"
      : "=&v"(a[0]), "=&v"(a[1]), "=&v"(a[2]), "=&v"(a[3]),
        "=&v"(a[4]), "=&v"(a[5]), "=&v"(a[6]), "=&v"(a[7]),
        "=&v"(a[8]), "=&v"(a[9]), "=&v"(a[10]), "=&v"(a[11]),
        "=&v"(a[12]), "=&v"(a[13]), "=&v"(a[14]), "=&v"(a[15])
      : "v"(base)
      : "memory");
}

// poison = all-ones u64 (4x bf16 0xFFFF = NaN, unreachable for h in (-1,1)).
// Retry rounds re-issue ALL chunks in parallel (one RT per round) — never
// the serial per-chunk revalidate that regressed round 2.
__device__ __forceinline__ void gl2_valid(u64 base, f32x4 a[16]) {
  gl2_16(base, a);
  int guard = 0;
  for (;;) {
    u64 bad = 0;
#pragma unroll
    for (int i = 0; i < 16; ++i) {
      union { f32x4 f; u64 w[2]; } u;
      u.f = a[i];
      bad |= (u.w[0] + 1 == 0) ? 1u : 0u;
      bad |= (u.w[1] + 1 == 0) ? 1u : 0u;
    }
    if (!bad) return;
    if (++guard > 20000) return;  // bounded: coherence-model failure -> NaN out, no hang
    __builtin_amdgcn_s_sleep(1);
    gl2_16(base, a);
  }
}

// remote (cross-XCD) gather via MALL-direct system-scope loads
__device__ __forceinline__ void rem_issue(const u64* __restrict__ b, f32x4 a[16]) {
#pragma unroll
  for (int i = 0; i < 16; ++i) {
    union { f32x4 f; u64 w[2]; } u;
    u.w[0] = __hip_atomic_load(b + i * 8, __ATOMIC_RELAXED, __HIP_MEMORY_SCOPE_SYSTEM);
    u.w[1] = __hip_atomic_load(b + i * 8 + 1, __ATOMIC_RELAXED, __HIP_MEMORY_SCOPE_SYSTEM);
    a[i] = u.f;
  }
}

__device__ __forceinline__ void rem_valid(const u64* __restrict__ b, f32x4 a[16]) {
  int guard = 0;
  for (;;) {
    u64 bad = 0;
#pragma unroll
    for (int i = 0; i < 16; ++i) {
      union { f32x4 f; u64 w[2]; } u;
      u.f = a[i];
      bad |= (u.w[0] + 1 == 0) ? 1u : 0u;
      bad |= (u.w[1] + 1 == 0) ? 1u : 0u;
    }
    if (!bad) return;
    if (++guard > 20000) return;
    __builtin_amdgcn_s_sleep(1);
    rem_issue(b, a);
  }
}

// ---------------- transpose+cast: WT[n][k] = bf16(W[k][n]) ----------------
__global__ __launch_bounds__(256) void transpose_k(const float* __restrict__ W,
                                                   bf16* __restrict__ WT,
                                                   int K, int N) {
  __shared__ bf16 tile[32][33];
  const int n0 = blockIdx.x * 32, k0 = blockIdx.y * 32;
  const int c = threadIdx.x & 31, r0 = threadIdx.x >> 5;
  for (int i = 0; i < 4; ++i) {
    int r = r0 + 8 * i;
    tile[r][c] = __float2bfloat16(W[(long)(k0 + r) * N + (n0 + c)]);
  }
  __syncthreads();
  for (int i = 0; i < 4; ++i) {
    int r = r0 + 8 * i;
    WT[(long)(n0 + r) * K + (k0 + c)] = tile[c][r];
  }
}

// ---------------- fused 2-layer persistent LSTM, XCD-local L2 dataflow ------
// 256 WGs x 256 thr, ~130KB LDS => exactly 1 WG/CU => exactly 32 WGs/XCD.
// Role by hardware placement: XCD0 = layer 0, XCD1 = layer 1, others exit.
// WG cg owns h-cols [16cg,16cg+16) (64 gate-cols), all 64 batch rows, full K
// in-WG => in-register eltwise (4 c-values/thread), no K-reduce.
// Recurrence h goes through the OWN XCD's L2: producers publish with plain
// sc0 stores (write-through L1 -> L2), consumers gather with sc0 loads
// (L1 bypass). Poison protocol (0xFF qwords) makes data self-signaling.
// Cross-layer h1 additionally published to MALL (system scope) for layer 1.
__global__ __launch_bounds__(256, 1) void lstm2_fused_k(
    const float* __restrict__ x,  // [64][512][264] f32
    const bf16* __restrict__ WiT0, const bf16* __restrict__ WhT0,
    const float* __restrict__ bias0,
    const bf16* __restrict__ WiT1, const bf16* __restrict__ WhT1,
    const float* __restrict__ bias1,
    char* __restrict__ h1_loc, char* __restrict__ h2_loc,  // [512][64][512] bf16
    u64* __restrict__ h1_rem,                              // [512][64][512] bf16
    u64* __restrict__ h2_rem,                              // [64][512] bf16 (t=511)
    u32* __restrict__ cnt)                                 // [8] u32, zeroed
{
  __shared__ short Wis[64 * 512];                 // 64KB (layer0 uses 32KB)
  __shared__ short Whs[64 * 512];                 // 64KB
  __shared__ __align__(16) short hstage[64 * 16]; // 2KB
  __shared__ int role_sh[2];

  const int tid = threadIdx.x;
  if (tid == 0) {
    u32 xcd;
    asm volatile("s_getreg_b32 %0, hwreg(HW_REG_XCC_ID)" : "=s"(xcd));
    u32 slot = __hip_atomic_fetch_add(&cnt[xcd & 7], 1u, __ATOMIC_RELAXED,
                                      __HIP_MEMORY_SCOPE_AGENT);
    role_sh[0] = (int)(xcd & 7);
    role_sh[1] = (int)slot;
  }
  __syncthreads();
  const int xcd = role_sh[0];
  const int slot = role_sh[1];
  if (!((xcd == 0 || xcd == 1) && slot < 32)) return;  // idle CUs exit
  const int layer = xcd;
  const int cg = slot;

  const int lane = tid & 63, wv = tid >> 6, q = lane >> 4, r = lane & 15;
  const int m = wv * 16 + r;  // batch row of this lane's A fragments
  const int swz = r & 7;

  const int K_in = layer ? 512 : 256;
  const bf16* WiT = layer ? WiT1 : WiT0;
  const bf16* WhT = layer ? WhT1 : WhT0;
  const float* bias = layer ? bias1 : bias0;
  char* hloc = layer ? h2_loc : h1_loc;

  // ---- stage weight slices into LDS, 16B-chunk XOR swizzle (kills the
  // row-stride-1024 16-way bank conflict on the B-frag ds_read_b128) ----
  for (int idx = tid; idx < 64 * 64; idx += 256) {
    const int j = idx >> 6, kc = idx & 63;  // j = gate*16 + local col
    const int zc = (j >> 4) * 512 + cg * 16 + (j & 15);
    *(bf16x8*)((char*)Whs + j * 1024 + ((kc ^ (j & 7)) << 4)) =
        *(const bf16x8*)(WhT + (long)zc * 512 + kc * 8);
  }
  const int csh = layer ? 6 : 5, cm = (1 << csh) - 1;
  const int rowb = K_in * 2;
  for (int idx = tid; idx < (64 << csh); idx += 256) {
    const int j = idx >> csh, kc = idx & cm;
    const int zc = (j >> 4) * 512 + cg * 16 + (j & 15);
    *(bf16x8*)((char*)Wis + j * rowb + ((kc ^ (j & 7)) << 4)) =
        *(const bf16x8*)(WiT + (long)zc * K_in + kc * 8);
  }

  float br[4];
#pragma unroll
  for (int g = 0; g < 4; ++g) br[g] = bias[g * 512 + cg * 16 + r];
  float creg[4] = {0.f, 0.f, 0.f, 0.f};

  // per-lane gather base into own layer's local h (row-major, +t*65536)
  const u64 gbase = (u64)hloc + (u64)m * 1024 + (u64)(q * 16);

  __syncthreads();

#pragma unroll 1
  for (int t = 0; t < 512; ++t) {
    f32x4 acc[4];
#pragma unroll
    for (int nf = 0; nf < 4; ++nf) {
      acc[nf][0] = 0.f; acc[nf][1] = 0.f; acc[nf][2] = 0.f; acc[nf][3] = 0.f;
    }

    if (layer == 0) {
      // x loads (nontemporal: keep the x stream from thrashing h lines in L2)
      const float* xr = x + ((long)m * 512 + t) * 264;
      f32x4 xf[8][2];
#pragma unroll
      for (int kt = 0; kt < 8; ++kt) {
        xf[kt][0] = __builtin_nontemporal_load((const f32x4*)(xr + kt * 32 + q * 8));
        xf[kt][1] = __builtin_nontemporal_load((const f32x4*)(xr + kt * 32 + q * 8 + 4));
      }
      f32x4 ah[16];
      if (t > 0) gl2_valid(gbase + (u64)(t - 1) * 65536, ah);
      bf16x8 ax[8];
#pragma unroll
      for (int kt = 0; kt < 8; ++kt) ax[kt] = pack8(xf[kt][0], xf[kt][1]);
#pragma unroll
      for (int nf = 0; nf < 4; ++nf) {
        const char* wb = (const char*)Wis + (nf * 16 + r) * 512;
#pragma unroll
        for (int kt = 0; kt < 8; ++kt)
          acc[nf] = MFMA16(ax[kt], *(const bf16x8*)(wb + (((kt * 4 + q) ^ swz) << 4)),
                           acc[nf]);
      }
      if (t > 0) {
#pragma unroll
        for (int nf = 0; nf < 4; ++nf) {
          const char* wb = (const char*)Whs + (nf * 16 + r) * 1024;
#pragma unroll
          for (int kt = 0; kt < 16; ++kt)
            acc[nf] = MFMA16(__builtin_bit_cast(bf16x8, ah[kt]),
                             *(const bf16x8*)(wb + (((kt * 4 + q) ^ swz) << 4)),
                             acc[nf]);
        }
      }
    } else {
      // issue the cross-XCD h1[t] gather first (longest latency), then the
      // critical own-recurrence h2[t-1] through local L2
      f32x4 ax[16], ah[16];
      const u64* remb = h1_rem + (u64)t * 8192 + (u64)(m * 128 + q * 2);
      rem_issue(remb, ax);
      if (t > 0) {
        gl2_valid(gbase + (u64)(t - 1) * 65536, ah);
#pragma unroll
        for (int nf = 0; nf < 4; ++nf) {
          const char* wb = (const char*)Whs + (nf * 16 + r) * 1024;
#pragma unroll
          for (int kt = 0; kt < 16; ++kt)
            acc[nf] = MFMA16(__builtin_bit_cast(bf16x8, ah[kt]),
                             *(const bf16x8*)(wb + (((kt * 4 + q) ^ swz) << 4)),
                             acc[nf]);
        }
      }
      rem_valid(remb, ax);
#pragma unroll
      for (int nf = 0; nf < 4; ++nf) {
        const char* wb = (const char*)Wis + (nf * 16 + r) * 1024;
#pragma unroll
        for (int kt = 0; kt < 16; ++kt)
          acc[nf] = MFMA16(__builtin_bit_cast(bf16x8, ax[kt]),
                           *(const bf16x8*)(wb + (((kt * 4 + q) ^ swz) << 4)),
                           acc[nf]);
      }
    }

    // ---- in-register eltwise: thread holds all 4 gates for 4 rows x 1 col
    // (D layout: row = wv*16 + q*4 + i, col = r; nf = gate) ----
#pragma unroll
    for (int i = 0; i < 4; ++i) {
      const float zi = acc[0][i] + br[0];
      const float zf = acc[1][i] + br[1];
      const float zg = acc[2][i] + br[2];
      const float zo = acc[3][i] + br[3];
      const float cnew = sigf(zf) * creg[i] + sigf(zi) * tanh_fast(zg);
      const float hnew = sigf(zo) * tanh_fast(cnew);
      creg[i] = cnew;
      hstage[(wv * 16 + q * 4 + i) * 16 + r] =
          __builtin_bit_cast(short, __float2bfloat16(hnew));
    }
    __syncthreads();

    // ---- publish: 64 rows x 32B. Local copy via sc0 stores (lands in own
    // XCD L2); layer-0 also to MALL for layer-1; layer-1 t=511 to MALL for
    // the head. Fire-and-forget: poison protocol needs no ordering. ----
    if (tid < 64) {
      const int row = tid;
      const f32x4 v0 = *(const f32x4*)(hstage + row * 16);
      const f32x4 v1 = *(const f32x4*)(hstage + row * 16 + 8);
      const u64 dl = (u64)hloc + (u64)t * 65536 + (u64)(row * 1024 + cg * 32);
      asm volatile(
          "global_store_dwordx4 %0, %1, off sc0\n\t"
          "global_store_dwordx4 %0, %2, off offset:16 sc0"
          :: "v"(dl), "v"(v0), "v"(v1) : "memory");
      union { f32x4 f[2]; u64 w[4]; } pu;
      pu.f[0] = v0; pu.f[1] = v1;
      if (layer == 0) {
        u64* dr = h1_rem + (u64)t * 8192 + (u64)(row * 128 + cg * 4);
        __hip_atomic_store(dr + 0, pu.w[0], __ATOMIC_RELAXED, __HIP_MEMORY_SCOPE_SYSTEM);
        __hip_atomic_store(dr + 1, pu.w[1], __ATOMIC_RELAXED, __HIP_MEMORY_SCOPE_SYSTEM);
        __hip_atomic_store(dr + 2, pu.w[2], __ATOMIC_RELAXED, __HIP_MEMORY_SCOPE_SYSTEM);
        __hip_atomic_store(dr + 3, pu.w[3], __ATOMIC_RELAXED, __HIP_MEMORY_SCOPE_SYSTEM);
      } else if (t == 511) {
        u64* dr = h2_rem + (u64)(row * 128 + cg * 4);
        __hip_atomic_store(dr + 0, pu.w[0], __ATOMIC_RELAXED, __HIP_MEMORY_SCOPE_SYSTEM);
        __hip_atomic_store(dr + 1, pu.w[1], __ATOMIC_RELAXED, __HIP_MEMORY_SCOPE_SYSTEM);
        __hip_atomic_store(dr + 2, pu.w[2], __ATOMIC_RELAXED, __HIP_MEMORY_SCOPE_SYSTEM);
        __hip_atomic_store(dr + 3, pu.w[3], __ATOMIC_RELAXED, __HIP_MEMORY_SCOPE_SYSTEM);
      }
    }
    __syncthreads();  // hstage read complete before next step overwrites
  }
}

// ---------------- dense head: concat -> 512 -> 256 -> 64 -> sigmoid ----------
__global__ __launch_bounds__(256) void head_k(
    const u64* __restrict__ h2_rem,  // [64][512] bf16 (t=511)
    const float* __restrict__ x,
    const float* __restrict__ Wd0, const float* __restrict__ bd0,
    const float* __restrict__ Wd1, const float* __restrict__ bd1,
    const float* __restrict__ Wf, const float* __restrict__ bfv,
    float* __restrict__ out) {
  const int b = blockIdx.x, tid = threadIdx.x;
  __shared__ float in0[520];
  __shared__ float d0s[512];
  __shared__ float d1s[256];
  if (tid < 64) {
    const int c = tid;  // 8-col chunk
    u64 w0 = __hip_atomic_load(h2_rem + (long)b * 128 + c * 2, __ATOMIC_RELAXED,
                               __HIP_MEMORY_SCOPE_SYSTEM);
    u64 w1 = __hip_atomic_load(h2_rem + (long)b * 128 + c * 2 + 1, __ATOMIC_RELAXED,
                               __HIP_MEMORY_SCOPE_SYSTEM);
    union { u64 w[2]; short sh[8]; } u;
    u.w[0] = w0; u.w[1] = w1;
    for (int j = 0; j < 8; ++j)
      in0[c * 8 + j] = __bfloat162float(__builtin_bit_cast(bf16, u.sh[j]));
  }
  if (tid < 8) in0[512 + tid] = x[((long)(b * 512 + 511)) * 264 + 256 + tid];
  __syncthreads();
  for (int j = tid; j < 512; j += 256) {
    float a = bd0[j];
    for (int k = 0; k < 520; ++k) a += in0[k] * Wd0[(long)k * 512 + j];
    d0s[j] = fmaxf(a, 0.f);
  }
  __syncthreads();
  if (tid < 256) {
    const int j = tid;
    float a = bd1[j];
    for (int k = 0; k < 512; ++k) a += d0s[k] * Wd1[(long)k * 256 + j];
    d1s[j] = fmaxf(a, 0.f);
  }
  __syncthreads();
  if (tid < 64) {
    const int j = tid;
    float a = bfv[j];
    for (int k = 0; k < 256; ++k) a += d1s[k] * Wf[(long)k * 64 + j];
    out[b * 64 + j] = sigf(a);
  }
}

extern "C" void kernel_launch(void* const* d_in, const int* in_sizes, int n_in,
                              void* d_out, int out_size, void* d_ws, size_t ws_size,
                              hipStream_t stream) {
  const float* x   = (const float*)d_in[0];
  const float* Wi0 = (const float*)d_in[1];
  const float* Wh0 = (const float*)d_in[2];
  const float* b0  = (const float*)d_in[3];
  const float* Wi1 = (const float*)d_in[4];
  const float* Wh1 = (const float*)d_in[5];
  const float* b1  = (const float*)d_in[6];
  const float* Wd0 = (const float*)d_in[7];
  const float* bd0 = (const float*)d_in[8];
  const float* Wd1 = (const float*)d_in[9];
  const float* bd1 = (const float*)d_in[10];
  const float* Wf  = (const float*)d_in[11];
  const float* bf_ = (const float*)d_in[12];
  float* out = (float*)d_out;

  char* ws = (char*)d_ws;
  size_t off = 0;
  auto carve = [&](size_t bytes) {
    void* p = ws + off;
    off += (bytes + 255) & ~(size_t)255;
    return p;
  };
  u32*  cnt  = (u32*)carve(256);
  bf16* WiT0 = (bf16*)carve((size_t)2048 * 256 * 2);
  bf16* WhT0 = (bf16*)carve((size_t)2048 * 512 * 2);
  bf16* WiT1 = (bf16*)carve((size_t)2048 * 512 * 2);
  bf16* WhT1 = (bf16*)carve((size_t)2048 * 512 * 2);
  char* h1_loc = (char*)carve((size_t)512 * 64 * 512 * 2);  // 32 MB
  char* h2_loc = (char*)carve((size_t)512 * 64 * 512 * 2);  // 32 MB
  u64*  h1_rem = (u64*)carve((size_t)512 * 64 * 512 * 2);   // 32 MB
  u64*  h2_rem = (u64*)carve((size_t)64 * 512 * 2);         // 64 KB

  (void)hipMemsetAsync(cnt, 0, 256, stream);
  // poison all h buffers: 0xFF bytes = bf16 NaN = "not yet written"
  (void)hipMemsetAsync(h1_loc,
                       0xFF,
                       (size_t)3 * 512 * 64 * 512 * 2 + (size_t)64 * 512 * 2,
                       stream);

  transpose_k<<<dim3(2048 / 32, 256 / 32), 256, 0, stream>>>(Wi0, WiT0, 256, 2048);
  transpose_k<<<dim3(2048 / 32, 512 / 32), 256, 0, stream>>>(Wh0, WhT0, 512, 2048);
  transpose_k<<<dim3(2048 / 32, 512 / 32), 256, 0, stream>>>(Wi1, WiT1, 512, 2048);
  transpose_k<<<dim3(2048 / 32, 512 / 32), 256, 0, stream>>>(Wh1, WhT1, 512, 2048);

  lstm2_fused_k<<<256, 256, 0, stream>>>(x, WiT0, WhT0, b0, WiT1, WhT1, b1,
                                         h1_loc, h2_loc, h1_rem, h2_rem, cnt);

  head_k<<<64, 256, 0, stream>>>(h2_rem, x, Wd0, bd0, Wd1, bd1, Wf, bf_, out);
}

// Round 5
// 2734.791 us; speedup vs baseline: 2.0250x; 2.0250x over previous
//
#include <hip/hip_runtime.h>
#include <hip/hip_bf16.h>

typedef __hip_bfloat16 bf16;
typedef short bf16x8 __attribute__((ext_vector_type(8)));
typedef float f32x4 __attribute__((ext_vector_type(4)));
typedef unsigned long long u64;
typedef unsigned int u32;

#define MFMA16(A, B, C) __builtin_amdgcn_mfma_f32_16x16x32_bf16(A, B, C, 0, 0, 0)

__device__ __forceinline__ float sigf(float x) { return 1.f / (1.f + __expf(-x)); }
__device__ __forceinline__ float tanh_fast(float x) { return 2.f / (1.f + __expf(-2.f * x)) - 1.f; }

// MALL-direct 16B load (two 8B system-relaxed atomics -> sc0 sc1; bypasses
// L1/L2). Used only where cache-dedup is useless (head_k).
__device__ __forceinline__ bf16x8 ld16(const u64* p) {
  u64 lo = __hip_atomic_load(p, __ATOMIC_RELAXED, __HIP_MEMORY_SCOPE_SYSTEM);
  u64 hi = __hip_atomic_load(p + 1, __ATOMIC_RELAXED, __HIP_MEMORY_SCOPE_SYSTEM);
  union { u64 q[2]; bf16x8 v; } u;
  u.q[0] = lo; u.q[1] = hi;
  return u.v;
}

// ---------------- transpose+cast: WT[n][k] = bf16(W[k][n]) ----------------
__global__ __launch_bounds__(256) void transpose_k(const float* __restrict__ W,
                                                   bf16* __restrict__ WT,
                                                   int K, int N) {
  __shared__ bf16 tile[32][33];
  const int n0 = blockIdx.x * 32, k0 = blockIdx.y * 32;
  const int c = threadIdx.x & 31, r0 = threadIdx.x >> 5;
  for (int i = 0; i < 4; ++i) {
    int r = r0 + 8 * i;
    tile[r][c] = __float2bfloat16(W[(long)(k0 + r) * N + (n0 + c)]);
  }
  __syncthreads();
  for (int i = 0; i < 4; ++i) {
    int r = r0 + 8 * i;
    WT[(long)(n0 + r) * K + (k0 + c)] = tile[c][r];
  }
}

// bulk gather of 16 A-chunks from step matrix mat (u64*, per-t base):
// chunk (slice s=4i+q, row m) = 16B at mat + (s*64 + m)*2.
// PLAIN CACHED loads: safe under the sentinel protocol (every h line is
// first-touched only after its producer's system-scope store reached MALL,
// and buffer_inv at kernel start dropped any pre-launch stale copies).
// The 16 WGs per XCD reading the same 64KB dedupe through the XCD L2:
// one MALL fill per XCD instead of 16 uncached re-reads.
__device__ __forceinline__ void gather16(const u64* __restrict__ mat, int m, int q,
                                         bf16x8* out) {
#pragma unroll
  for (int i = 0; i < 16; ++i) {
    const int s = i * 4 + q;
    out[i] = *(const bf16x8*)(mat + ((long)(s << 6) + m) * 2);
  }
}

// ---------------- fused 2-layer persistent LSTM, sentinel dataflow ----------
// 128 WGs x 256 thr. layer = blk>>6, w = blk&63 owns h-cols [8w,8w+8).
// h1D/h2D: [512][64 slices][64 rows][8] bf16 (write-once, full history).
// sent0/sent1: [512][64] u32, zeroed; producer w release-stores sent[t][w]=1
// after its 1KB data slice (release => vmcnt(0) drain: data at MALL first).
// Only wave 0 polls (one 64-lane load covers all 64 producers), then
// __syncthreads releases the WG. Consumers gather with CACHED loads (L2
// dedup); producers publish with system-scope stores (straight to MALL).
__global__ __launch_bounds__(256, 1) void lstm2_fused_k(
    const float* __restrict__ x,  // [64][512][264] f32
    const bf16* __restrict__ WiT0, const bf16* __restrict__ WhT0,
    const float* __restrict__ bias0,
    const bf16* __restrict__ WiT1, const bf16* __restrict__ WhT1,
    const float* __restrict__ bias1,
    u64* __restrict__ h1D, u64* __restrict__ h2D,
    u32* __restrict__ sent)  // [2][512][64] u32, zeroed
{
  __shared__ short Wis[32 * 520];
  __shared__ short Whs[32 * 520];
  __shared__ float zs[32 * 66];
  __shared__ __align__(16) bf16 hstage[64 * 8];

  const int layer = blockIdx.x >> 6;
  const int w = blockIdx.x & 63;
  const int tid = threadIdx.x;
  const int lane = tid & 63;
  const int wv = tid >> 6;
  const int q = lane >> 4;
  const int r = lane & 15;

  // Drop any stale clean lines (prior iterations / harness re-poison) from
  // this CU's L1 and this XCD's L2 so all h first-touches fetch from MALL.
  // One-time cost: weights/x refetch. sc0 = L1, sc1 = L2.
  if (tid == 0) asm volatile("buffer_inv sc0 sc1" ::: "memory");

  const int K_in = layer ? 512 : 256;
  const bf16* WiT = layer ? WiT1 : WiT0;
  const bf16* WhT = layer ? WhT1 : WhT0;
  const float* bias = layer ? bias1 : bias0;
  u32* s0 = sent;                 // layer-0 sentinels
  u32* s1 = sent + 512 * 64;      // layer-1 sentinels
  u64* houtD = layer ? h2D : h1D;
  u32* smy = (layer ? s1 : s0);

  // ---- stage weight slices into LDS (reused all 512 steps) ----
  for (int idx = tid; idx < 32 * 64; idx += 256) {
    const int j = idx >> 6, kc = idx & 63;
    const int zc = (j >> 3) * 512 + w * 8 + (j & 7);
    *(bf16x8*)(Whs + j * 520 + kc * 8) = *(const bf16x8*)(WhT + (long)zc * 512 + kc * 8);
  }
  const int csh = layer ? 6 : 5;
  const int cmask = (1 << csh) - 1;
  for (int idx = tid; idx < (32 << csh); idx += 256) {
    const int j = idx >> csh, kc = idx & cmask;
    const int zc = (j >> 3) * 512 + w * 8 + (j & 7);
    *(bf16x8*)(Wis + j * 520 + kc * 8) = *(const bf16x8*)(WiT + (long)zc * K_in + kc * 8);
  }

  const int m = wv * 16 + r;
  const short* wi0p = Wis + r * 520;
  const short* wi1p = Wis + (16 + r) * 520;
  const short* wh0p = Whs + r * 520;
  const short* wh1p = Whs + (16 + r) * 520;

  const int gb = tid & 63;
  const int gc0 = tid >> 6;
  float bias_r[2][4];
  for (int s = 0; s < 2; ++s)
    for (int g = 0; g < 4; ++g)
      bias_r[s][g] = bias[g * 512 + w * 8 + gc0 + 4 * s];
  float creg[2] = {0.f, 0.f};

  __syncthreads();

  for (int t = 0; t < 512; ++t) {
    f32x4 acc0 = {0.f, 0.f, 0.f, 0.f};
    f32x4 acc1 = {0.f, 0.f, 0.f, 0.f};

    if (layer == 0) {
      // x-part first: independent of any producer, overlaps others' step t-1
      bf16x8 ax[8];
      const float* row = x + ((long)m * 512 + t) * 264;
#pragma unroll
      for (int i = 0; i < 8; ++i) {
        const float4 f0 = *(const float4*)(row + i * 32 + q * 8);
        const float4 f1 = *(const float4*)(row + i * 32 + q * 8 + 4);
        union { short s[8]; bf16x8 v8; } o;
        o.s[0] = __builtin_bit_cast(short, __float2bfloat16(f0.x));
        o.s[1] = __builtin_bit_cast(short, __float2bfloat16(f0.y));
        o.s[2] = __builtin_bit_cast(short, __float2bfloat16(f0.z));
        o.s[3] = __builtin_bit_cast(short, __float2bfloat16(f0.w));
        o.s[4] = __builtin_bit_cast(short, __float2bfloat16(f1.x));
        o.s[5] = __builtin_bit_cast(short, __float2bfloat16(f1.y));
        o.s[6] = __builtin_bit_cast(short, __float2bfloat16(f1.z));
        o.s[7] = __builtin_bit_cast(short, __float2bfloat16(f1.w));
        ax[i] = o.v8;
      }
#pragma unroll
      for (int i = 0; i < 8; ++i) {
        const int kk = i * 32;
        acc0 = MFMA16(ax[i], *(const bf16x8*)(wi0p + kk + q * 8), acc0);
        acc1 = MFMA16(ax[i], *(const bf16x8*)(wi1p + kk + q * 8), acc1);
      }
      if (t > 0) {
        if (tid < 64) {  // wave 0 polls all 64 producer sentinels of h1[t-1]
          const u32* sp = s0 + (t - 1) * 64 + tid;
          while (__ballot(__hip_atomic_load(sp, __ATOMIC_RELAXED,
                                            __HIP_MEMORY_SCOPE_SYSTEM) != 0) != ~0ull)
            __builtin_amdgcn_s_sleep(2);
        }
        __syncthreads();
        bf16x8 ah[16];
        gather16(h1D + (long)(t - 1) * 8192, m, q, ah);
#pragma unroll
        for (int i = 0; i < 16; ++i) {
          const int kk = i * 32;
          acc0 = MFMA16(ah[i], *(const bf16x8*)(wh0p + kk + q * 8), acc0);
          acc1 = MFMA16(ah[i], *(const bf16x8*)(wh1p + kk + q * 8), acc1);
        }
      }
    } else {
      // x-part = h1[t]; do it first (layer-0 runs ahead), leave own-layer
      // recurrence (the true critical edge) for last
      if (tid < 64) {
        const u32* sp = s0 + t * 64 + tid;
        while (__ballot(__hip_atomic_load(sp, __ATOMIC_RELAXED,
                                          __HIP_MEMORY_SCOPE_SYSTEM) != 0) != ~0ull)
          __builtin_amdgcn_s_sleep(2);
      }
      __syncthreads();
      bf16x8 ax[16];
      gather16(h1D + (long)t * 8192, m, q, ax);
#pragma unroll
      for (int i = 0; i < 16; ++i) {
        const int kk = i * 32;
        acc0 = MFMA16(ax[i], *(const bf16x8*)(wi0p + kk + q * 8), acc0);
        acc1 = MFMA16(ax[i], *(const bf16x8*)(wi1p + kk + q * 8), acc1);
      }
      if (t > 0) {
        if (tid < 64) {
          const u32* sp = s1 + (t - 1) * 64 + tid;
          while (__ballot(__hip_atomic_load(sp, __ATOMIC_RELAXED,
                                            __HIP_MEMORY_SCOPE_SYSTEM) != 0) != ~0ull)
            __builtin_amdgcn_s_sleep(2);
        }
        __syncthreads();
        bf16x8 ah[16];
        gather16(h2D + (long)(t - 1) * 8192, m, q, ah);
#pragma unroll
        for (int i = 0; i < 16; ++i) {
          const int kk = i * 32;
          acc0 = MFMA16(ah[i], *(const bf16x8*)(wh0p + kk + q * 8), acc0);
          acc1 = MFMA16(ah[i], *(const bf16x8*)(wh1p + kk + q * 8), acc1);
        }
      }
    }

    // D-layout: row(b)=wv*16+q*4+i, col(n)=ntile*16+r  [m89-verified]
    {
      const int brow = wv * 16 + q * 4;
      for (int i = 0; i < 4; ++i) zs[r * 66 + brow + i] = acc0[i];
      for (int i = 0; i < 4; ++i) zs[(16 + r) * 66 + brow + i] = acc1[i];
    }
    __syncthreads();

    for (int s = 0; s < 2; ++s) {
      const int c = gc0 + 4 * s;
      const float zi = zs[(c)*66 + gb] + bias_r[s][0];
      const float zf = zs[(8 + c) * 66 + gb] + bias_r[s][1];
      const float zg = zs[(16 + c) * 66 + gb] + bias_r[s][2];
      const float zo = zs[(24 + c) * 66 + gb] + bias_r[s][3];
      const float cnew = sigf(zf) * creg[s] + sigf(zi) * tanh_fast(zg);
      const float hnew = sigf(zo) * tanh_fast(cnew);
      creg[s] = cnew;
      hstage[gb * 8 + c] = __float2bfloat16(hnew);
    }
    __syncthreads();

    // publish: wave 0 stores the 1KB slice, then lane 0 release-stores the
    // sentinel (release => s_waitcnt vmcnt(0): data at MALL before sentinel)
    if (tid < 64) {
      const u64* src = (const u64*)(hstage + tid * 8);
      u64* dst = houtD + (((long)t * 64 + w) * 64 + tid) * 2;
      __hip_atomic_store(dst, src[0], __ATOMIC_RELAXED, __HIP_MEMORY_SCOPE_SYSTEM);
      __hip_atomic_store(dst + 1, src[1], __ATOMIC_RELAXED, __HIP_MEMORY_SCOPE_SYSTEM);
    }
    if (tid == 0)
      __hip_atomic_store(smy + t * 64 + w, 1u, __ATOMIC_RELEASE, __HIP_MEMORY_SCOPE_AGENT);
  }
}

// ---------------- dense head: concat -> 512 -> 256 -> 64 -> sigmoid ----------
__global__ __launch_bounds__(256) void head_k(
    const u64* __restrict__ h2D,  // [512][64][64][8] bf16; reads t=511
    const float* __restrict__ x,
    const float* __restrict__ Wd0, const float* __restrict__ bd0,
    const float* __restrict__ Wd1, const float* __restrict__ bd1,
    const float* __restrict__ Wf, const float* __restrict__ bfv,
    float* __restrict__ out) {
  const int b = blockIdx.x, tid = threadIdx.x;
  __shared__ float in0[520];
  __shared__ float d0s[512];
  __shared__ float d1s[256];
  if (tid < 64) {
    const int s = tid;
    bf16x8 v = ld16(h2D + (((long)511 * 64 + s) * 64 + b) * 2);
    union { bf16x8 v8; short sh[8]; } u;
    u.v8 = v;
    for (int j = 0; j < 8; ++j)
      in0[s * 8 + j] = __bfloat162float(__builtin_bit_cast(bf16, u.sh[j]));
  }
  if (tid < 8) in0[512 + tid] = x[((long)(b * 512 + 511)) * 264 + 256 + tid];
  __syncthreads();
  for (int j = tid; j < 512; j += 256) {
    float a = bd0[j];
    for (int k = 0; k < 520; ++k) a += in0[k] * Wd0[(long)k * 512 + j];
    d0s[j] = fmaxf(a, 0.f);
  }
  __syncthreads();
  if (tid < 256) {
    const int j = tid;
    float a = bd1[j];
    for (int k = 0; k < 512; ++k) a += d0s[k] * Wd1[(long)k * 256 + j];
    d1s[j] = fmaxf(a, 0.f);
  }
  __syncthreads();
  if (tid < 64) {
    const int j = tid;
    float a = bfv[j];
    for (int k = 0; k < 256; ++k) a += d1s[k] * Wf[(long)k * 64 + j];
    out[b * 64 + j] = sigf(a);
  }
}

extern "C" void kernel_launch(void* const* d_in, const int* in_sizes, int n_in,
                              void* d_out, int out_size, void* d_ws, size_t ws_size,
                              hipStream_t stream) {
  const float* x   = (const float*)d_in[0];
  const float* Wi0 = (const float*)d_in[1];
  const float* Wh0 = (const float*)d_in[2];
  const float* b0  = (const float*)d_in[3];
  const float* Wi1 = (const float*)d_in[4];
  const float* Wh1 = (const float*)d_in[5];
  const float* b1  = (const float*)d_in[6];
  const float* Wd0 = (const float*)d_in[7];
  const float* bd0 = (const float*)d_in[8];
  const float* Wd1 = (const float*)d_in[9];
  const float* bd1 = (const float*)d_in[10];
  const float* Wf  = (const float*)d_in[11];
  const float* bf_ = (const float*)d_in[12];
  float* out = (float*)d_out;

  char* ws = (char*)d_ws;
  size_t off = 0;
  auto carve = [&](size_t bytes) {
    void* p = ws + off;
    off += (bytes + 255) & ~(size_t)255;
    return p;
  };
  u32* sent = (u32*)carve((size_t)2 * 512 * 64 * 4);  // 256 KB sentinels
  const size_t zero_bytes = off;
  bf16* WiT0 = (bf16*)carve((size_t)2048 * 256 * 2);
  bf16* WhT0 = (bf16*)carve((size_t)2048 * 512 * 2);
  bf16* WiT1 = (bf16*)carve((size_t)2048 * 512 * 2);
  bf16* WhT1 = (bf16*)carve((size_t)2048 * 512 * 2);
  u64*  h1D  = (u64*)carve((size_t)512 * 64 * 64 * 16);  // 32 MB bf16 history
  u64*  h2D  = (u64*)carve((size_t)512 * 64 * 64 * 16);  // 32 MB bf16 history

  (void)hipMemsetAsync(sent, 0, zero_bytes, stream);

  transpose_k<<<dim3(2048 / 32, 256 / 32), 256, 0, stream>>>(Wi0, WiT0, 256, 2048);
  transpose_k<<<dim3(2048 / 32, 512 / 32), 256, 0, stream>>>(Wh0, WhT0, 512, 2048);
  transpose_k<<<dim3(2048 / 32, 512 / 32), 256, 0, stream>>>(Wi1, WiT1, 512, 2048);
  transpose_k<<<dim3(2048 / 32, 512 / 32), 256, 0, stream>>>(Wh1, WhT1, 512, 2048);

  lstm2_fused_k<<<128, 256, 0, stream>>>(x, WiT0, WhT0, b0, WiT1, WhT1, b1,
                                         h1D, h2D, sent);

  head_k<<<64, 256, 0, stream>>>(h2D, x, Wd0, bd0, Wd1, bd1, Wf, bf_, out);
}